// Round 18
// baseline (192.765 us; speedup 1.0000x reference)
//
#include <hip/hip_runtime.h>

#define STEPS 64
#define NUM_CPU 4
#define AGENTS 64
#define PHASES 8
#define NN (STEPS*NUM_CPU*AGENTS*PHASES)   // 131072 nodes
#define NE (NN*8)                          // 1048576 edges
#define ROWS (NN/PHASES)                   // 16384 MLP rows

typedef __attribute__((ext_vector_type(8))) short bf16x8;
typedef __attribute__((ext_vector_type(4))) float f32x4;

__device__ inline unsigned short f2bf(float x) {
    unsigned int b = __float_as_uint(x);
    return (unsigned short)((b + 0x7FFF + ((b >> 16) & 1)) >> 16);
}
__device__ inline float bf2f(unsigned short h) {
    return __uint_as_float(((unsigned int)h) << 16);
}
__device__ inline void split8(const float* a, bf16x8& hi, bf16x8& lo) {
#pragma unroll
    for (int i = 0; i < 8; ++i) {
        float x = a[i];
        unsigned short h = f2bf(x);
        hi[i] = (short)h;
        lo[i] = (short)f2bf(x - bf2f(h));
    }
}

// fragment-tile offset: value (n, k) lives at
//   ((n>>4)*TK + (k>>5))*512 + ((n&15) + 16*((k>>3)&3))*8 + (k&7),  TK=K/32.

// ===== combined prep: weight tiles + obs->bf16 table + coarse hist ======
__device__ inline void prep1(const float* __restrict__ src,
                             unsigned short* __restrict__ dhi,
                             unsigned short* __restrict__ dlo,
                             int gid, int nshift, int nmask, int tk) {
    int k = gid >> nshift, n = gid & nmask;
    float x = src[gid];
    unsigned short h = f2bf(x);
    size_t o = ((size_t)(n >> 4) * tk + (k >> 5)) * 512
             + ((n & 15) + 16 * ((k >> 3) & 3)) * 8 + (k & 7);
    dhi[o] = h;
    dlo[o] = f2bf(x - bf2f(h));
}

__global__ __launch_bounds__(256) void k_prepall(const float* __restrict__ w0,
                                                 unsigned short* __restrict__ w0hi,
                                                 unsigned short* __restrict__ w0lo,
                                                 const float* __restrict__ w1,
                                                 unsigned short* __restrict__ w1hi,
                                                 unsigned short* __restrict__ w1lo,
                                                 const float* __restrict__ ws1,
                                                 unsigned short* __restrict__ ws1hi,
                                                 unsigned short* __restrict__ ws1lo,
                                                 const float* __restrict__ wn1,
                                                 unsigned short* __restrict__ wn1hi,
                                                 unsigned short* __restrict__ wn1lo,
                                                 const float* __restrict__ obs,
                                                 unsigned short* __restrict__ obsb,
                                                 const int* __restrict__ edge,
                                                 int* __restrict__ bcnt) {
    __shared__ int c[256];
    const int blk = blockIdx.x, tid = threadIdx.x;
    if (blk < 1024) {
        prep1(w0, w0hi, w0lo, blk * 256 + tid, 8, 255, 32);
    } else if (blk < 1280) {
        prep1(w1, w1hi, w1lo, (blk - 1024) * 256 + tid, 8, 255, 8);
    } else if (blk < 1312) {
        prep1(ws1, ws1hi, ws1lo, (blk - 1280) * 256 + tid, 6, 63, 4);
    } else if (blk < 1344) {
        prep1(wn1, wn1hi, wn1lo, (blk - 1312) * 256 + tid, 6, 63, 4);
    } else if (blk < 2368) {
        int gid = (blk - 1344) * 256 + tid;
        const float* src = obs + (size_t)gid * 8;
        unsigned short v[8];
#pragma unroll
        for (int i = 0; i < 8; ++i) v[i] = f2bf(src[i]);
        *(uint4*)&obsb[(size_t)gid * 8] = *(const uint4*)v;
    } else {
        c[tid] = 0;
        __syncthreads();
        const int base = (blk - 2368) * 1024;
        for (int i = tid; i < 1024; i += 256)
            atomicAdd(&c[edge[NE + base + i] >> 9], 1);
        __syncthreads();
        atomicAdd(&bcnt[tid], c[tid]);
    }
}

__global__ __launch_bounds__(256) void k_scan256(const int* __restrict__ bcnt,
                                                 int* __restrict__ bbase,
                                                 int* __restrict__ bcur) {
    __shared__ int s[256];
    const int t = threadIdx.x;
    int v = bcnt[t];
    s[t] = v;
    __syncthreads();
    for (int d = 1; d < 256; d <<= 1) {
        int x = (t >= d) ? s[t - d] : 0;
        __syncthreads();
        s[t] += x;
        __syncthreads();
    }
    int ex = s[t] - v;
    bbase[t] = ex;
    bcur[t] = ex;
    if (t == 255) bbase[256] = s[255];
}

__global__ __launch_bounds__(256) void k_bucket(const int* __restrict__ edge,
                                                int* __restrict__ bcur,
                                                int2* __restrict__ pairs) {
    __shared__ int rs[4096], rd[4096];
    __shared__ int ss[4096], sd[4096];
    __shared__ int cnt[256], lbase[256], lcur[256], gbase[256];
    const int tid = threadIdx.x;
    const int e0 = blockIdx.x * 4096;
    cnt[tid] = 0;
    for (int i = tid; i < 4096; i += 256) {
        rs[i] = edge[e0 + i];
        rd[i] = edge[NE + e0 + i];
    }
    __syncthreads();
    for (int i = tid; i < 4096; i += 256) atomicAdd(&cnt[rd[i] >> 9], 1);
    __syncthreads();
    {
        const int v = cnt[tid];
        lbase[tid] = v;
        __syncthreads();
        for (int d = 1; d < 256; d <<= 1) {
            int x = (tid >= d) ? lbase[tid - d] : 0;
            __syncthreads();
            lbase[tid] += x;
            __syncthreads();
        }
        const int ex = lbase[tid] - v;
        lbase[tid] = ex;
        lcur[tid] = ex;
        gbase[tid] = atomicAdd(&bcur[tid], v);
    }
    __syncthreads();
    for (int i = tid; i < 4096; i += 256) {
        int b = rd[i] >> 9;
        int p = atomicAdd(&lcur[b], 1);
        ss[p] = rs[i];
        sd[p] = rd[i];
    }
    __syncthreads();
    for (int j = tid; j < 4096; j += 256) {
        int b = sd[j] >> 9;
        pairs[gbase[b] + (j - lbase[b])] = (int2){ss[j], sd[j]};
    }
}

// ==== per-bucket degree histogram + scan -> off (merged, no deg array) ==
__global__ __launch_bounds__(256) void k_degscan(const int2* __restrict__ pairs,
                                                 const int* __restrict__ bbase,
                                                 int* __restrict__ off) {
    __shared__ int c[512];
    __shared__ int s[256];
    const int b = blockIdx.x, tid = threadIdx.x;
    c[tid] = 0; c[tid + 256] = 0;
    __syncthreads();
    const int n0 = bbase[b], n1 = bbase[b + 1];
    for (int j = n0 + tid; j < n1; j += 256) atomicAdd(&c[pairs[j].y & 511], 1);
    __syncthreads();
    const int vx = c[tid * 2], vy = c[tid * 2 + 1];
    const int pair = vx + vy;
    s[tid] = pair;
    __syncthreads();
    for (int d = 1; d < 256; d <<= 1) {
        int x = (tid >= d) ? s[tid - d] : 0;
        __syncthreads();
        s[tid] += x;
        __syncthreads();
    }
    int pre = bbase[b] + s[tid] - pair;
    int i0 = b * 512 + tid * 2;
    off[i0] = pre;
    off[i0 + 1] = pre + vx;
    if (b == 255 && tid == 255) off[NN] = pre + pair;
}

__global__ __launch_bounds__(256) void k_sort(const int2* __restrict__ pairs,
                                              const int* __restrict__ bbase,
                                              const int* __restrict__ off,
                                              int* __restrict__ csr) {
    __shared__ int lcur[512];
    __shared__ int sorted[6144];
    const int b = blockIdx.x, tid = threadIdx.x;
    const int off0 = off[b * 512];
    lcur[tid] = off[b * 512 + tid] - off0;
    lcur[tid + 256] = off[b * 512 + 256 + tid] - off0;
    __syncthreads();
    const int n0 = bbase[b], n1 = bbase[b + 1];
    for (int j = n0 + tid; j < n1; j += 256) {
        int2 p = pairs[j];
        int loc = atomicAdd(&lcur[p.y & 511], 1);
        sorted[loc] = p.x;
    }
    __syncthreads();
    const int cnt = n1 - n0;
    for (int j = tid; j < cnt; j += 256) csr[off0 + j] = sorted[j];
}

// ====== layer 0: per-node aggregate of obs (bf16 table, 8-deep ILP) =====
__global__ __launch_bounds__(256) void k_agg0(const unsigned short* __restrict__ obsb,
                                              const int* __restrict__ off,
                                              const int* __restrict__ csr,
                                              float* __restrict__ agg0) {
    int gid = blockIdx.x * 256 + threadIdx.x;
    int node = gid >> 4, f = gid & 15;
    if (node >= NN) return;
    int e0 = off[node], e1 = off[node + 1];
    float s0 = 0.f, s1 = 0.f, s2 = 0.f, s3 = 0.f;
    float s4 = 0.f, s5 = 0.f, s6 = 0.f, s7 = 0.f;
    int e = e0;
    for (; e + 7 < e1; e += 8) {
        s0 += bf2f(obsb[csr[e] * 16 + f]);
        s1 += bf2f(obsb[csr[e + 1] * 16 + f]);
        s2 += bf2f(obsb[csr[e + 2] * 16 + f]);
        s3 += bf2f(obsb[csr[e + 3] * 16 + f]);
        s4 += bf2f(obsb[csr[e + 4] * 16 + f]);
        s5 += bf2f(obsb[csr[e + 5] * 16 + f]);
        s6 += bf2f(obsb[csr[e + 6] * 16 + f]);
        s7 += bf2f(obsb[csr[e + 7] * 16 + f]);
    }
    for (; e + 3 < e1; e += 4) {
        s0 += bf2f(obsb[csr[e] * 16 + f]);
        s1 += bf2f(obsb[csr[e + 1] * 16 + f]);
        s2 += bf2f(obsb[csr[e + 2] * 16 + f]);
        s3 += bf2f(obsb[csr[e + 3] * 16 + f]);
    }
    for (; e < e1; ++e) s0 += bf2f(obsb[csr[e] * 16 + f]);
    agg0[node * 16 + f] = ((s0 + s1) + (s2 + s3)) + ((s4 + s5) + (s6 + s7));
}

// ==== FUSED layer-0 transform + layer-1 GEMMs (MFMA hi/lo), 64 nodes/blk
__global__ __launch_bounds__(256) void k_f01(const float* __restrict__ obs,
                                             const float* __restrict__ agg0,
                                             const int* __restrict__ off,
                                             const float* __restrict__ ws0,
                                             const float* __restrict__ bs0,
                                             const float* __restrict__ wn0,
                                             const float* __restrict__ bn0,
                                             const unsigned short* __restrict__ ws1tt_hi,
                                             const unsigned short* __restrict__ ws1tt_lo,
                                             const unsigned short* __restrict__ wn1tt_hi,
                                             const unsigned short* __restrict__ wn1tt_lo,
                                             const float* __restrict__ bs1,
                                             unsigned short* __restrict__ h1b,
                                             unsigned short* __restrict__ y1b) {
    __shared__ float w0s[16 * 64];
    __shared__ float w0n[16 * 64];
    __shared__ float biasS[64], biasN[64];
    __shared__ __align__(16) unsigned short s_hi[16 * 256];
    const int tid = threadIdx.x;
    for (int t = tid; t < 1024; t += 256) { w0s[t] = ws0[t]; w0n[t] = wn0[t]; }
    if (tid < 64) { biasS[tid] = bs0[tid]; biasN[tid] = bn0[tid]; }
    __syncthreads();

    const int wv = tid >> 6, l = tid & 63;
    const int lr = l & 15, lg = l >> 4;
    const int nt = blockIdx.x;
    const int tile = nt * 4 + wv;
    const int node = tile * 16 + lr;

    float xin[16], ain[16];
    {
        const float* xp = obs + (size_t)node * 16;
        const float* ap = agg0 + (size_t)node * 16;
#pragma unroll
        for (int q = 0; q < 4; ++q) {
            *(float4*)&xin[q * 4] = *(const float4*)(xp + q * 4);
            *(float4*)&ain[q * 4] = *(const float4*)(ap + q * 4);
        }
        int d = off[node + 1] - off[node];
        float inv = 1.f / (float)(d < 1 ? 1 : d);
#pragma unroll
        for (int k = 0; k < 16; ++k) ain[k] *= inv;
    }

    bf16x8 ahi[4], alo[4];
#pragma unroll
    for (int kc = 0; kc < 4; ++kc) {
        const int half = kc >> 1;
        const int jb = (kc & 1) * 32 + lg * 8;
        const float* w = half ? w0n : w0s;
        const float* bias = half ? biasN : biasS;
        const float* in = half ? ain : xin;
        float a8[8];
#pragma unroll
        for (int i = 0; i < 8; ++i) a8[i] = bias[jb + i];
        for (int k = 0; k < 16; ++k) {
            const float xv = in[k];
            const float4 wa = *(const float4*)&w[k * 64 + jb];
            const float4 wb = *(const float4*)&w[k * 64 + jb + 4];
            a8[0] += xv * wa.x; a8[1] += xv * wa.y;
            a8[2] += xv * wa.z; a8[3] += xv * wa.w;
            a8[4] += xv * wb.x; a8[5] += xv * wb.y;
            a8[6] += xv * wb.z; a8[7] += xv * wb.w;
        }
#pragma unroll
        for (int i = 0; i < 8; ++i) a8[i] = a8[i] > 0.f ? a8[i] : 0.f;
        split8(a8, ahi[kc], alo[kc]);
    }

    f32x4 acc[8];
#pragma unroll
    for (int t = 0; t < 8; ++t) {
        float bv = (t < 4) ? bs1[t * 16 + lr] : 0.f;
        acc[t] = (f32x4){bv, bv, bv, bv};
    }
#pragma unroll
    for (int kc = 0; kc < 4; ++kc) {
#pragma unroll
        for (int t = 0; t < 8; ++t) {
            const unsigned short* bh = (t < 4) ? ws1tt_hi : wn1tt_hi;
            const unsigned short* bl = (t < 4) ? ws1tt_lo : wn1tt_lo;
            size_t boff = ((size_t)(t & 3) * 4 + kc) * 512 + l * 8;
            bf16x8 bhi = *(const bf16x8*)(bh + boff);
            bf16x8 blo = *(const bf16x8*)(bl + boff);
            acc[t] = __builtin_amdgcn_mfma_f32_16x16x32_bf16(ahi[kc], bhi, acc[t], 0, 0, 0);
            acc[t] = __builtin_amdgcn_mfma_f32_16x16x32_bf16(alo[kc], bhi, acc[t], 0, 0, 0);
            acc[t] = __builtin_amdgcn_mfma_f32_16x16x32_bf16(ahi[kc], blo, acc[t], 0, 0, 0);
        }
    }

#pragma unroll
    for (int t = 0; t < 8; ++t) {
#pragma unroll
        for (int r = 0; r < 4; ++r) {
            const int nl = wv * 16 + lg * 4 + r;
            const size_t gnode = (size_t)nt * 64 + nl;
            if (t < 4) {
                float v = acc[t][r];
                v = v > 0.f ? v : 0.f;
                const int c = t * 16 + lr;
                const int lt = (nl & 7) * 2 + (c >> 5);
                const int o = lt * 256 + ((nl >> 3) + 8 * ((c >> 3) & 3)) * 8 + (c & 7);
                s_hi[o] = f2bf(v);
            } else {
                y1b[gnode * 64 + (t - 4) * 16 + lr] = f2bf(acc[t][r]);
            }
        }
    }
    __syncthreads();
    for (int idx = tid; idx < 512; idx += 256) {
        int lt = idx >> 5, sub = idx & 31;
        int ln = sub & 7, qq = sub >> 3;
        size_t g = (size_t)(nt >> 1) * 32 + (lt >> 1) * 4 + (lt & 1);
        size_t dst = g * 512 + (size_t)((nt & 1) * 8 + ln + 16 * qq) * 8;
        int src = lt * 256 + (ln + 8 * qq) * 8;
        *(uint4*)&h1b[dst] = *(const uint4*)&s_hi[src];
    }
}

// ==== layer-1 neighbor aggregate (uint4 gather: 8 lanes/row x 8 edges) ==
__global__ __launch_bounds__(256) void k_agg1f(const unsigned short* __restrict__ y1b,
                                               const int* __restrict__ off,
                                               const int* __restrict__ csr,
                                               const float* __restrict__ bn1,
                                               unsigned short* __restrict__ h1b) {
    __shared__ __align__(16) unsigned short s_hi[16 * 256];
    const int tid = threadIdx.x;
    const int wv = tid >> 6, lane = tid & 63;
    const int c8 = lane & 7, eo = lane >> 3;       // col-group of 8, edge-offset
    const int nt = blockIdx.x;
    const int cbase = c8 * 8;
    float bias8[8];
#pragma unroll
    for (int i = 0; i < 8; ++i) bias8[i] = bn1[cbase + i];

    for (int i = 0; i < 16; ++i) {
        const int nl = wv * 16 + i;
        const int node = nt * 64 + nl;
        const int e0 = off[node], e1 = off[node + 1];
        float s[8];
#pragma unroll
        for (int k = 0; k < 8; ++k) s[k] = 0.f;
        int e = e0;
        for (; e + 7 < e1; e += 8) {
            uint4 v = *(const uint4*)&y1b[(size_t)csr[e + eo] * 64 + cbase];
            s[0] += bf2f((unsigned short)v.x); s[1] += bf2f((unsigned short)(v.x >> 16));
            s[2] += bf2f((unsigned short)v.y); s[3] += bf2f((unsigned short)(v.y >> 16));
            s[4] += bf2f((unsigned short)v.z); s[5] += bf2f((unsigned short)(v.z >> 16));
            s[6] += bf2f((unsigned short)v.w); s[7] += bf2f((unsigned short)(v.w >> 16));
        }
        if (eo < e1 - e) {
            uint4 v = *(const uint4*)&y1b[(size_t)csr[e + eo] * 64 + cbase];
            s[0] += bf2f((unsigned short)v.x); s[1] += bf2f((unsigned short)(v.x >> 16));
            s[2] += bf2f((unsigned short)v.y); s[3] += bf2f((unsigned short)(v.y >> 16));
            s[4] += bf2f((unsigned short)v.z); s[5] += bf2f((unsigned short)(v.z >> 16));
            s[6] += bf2f((unsigned short)v.w); s[7] += bf2f((unsigned short)(v.w >> 16));
        }
#pragma unroll
        for (int k = 0; k < 8; ++k) {
            s[k] += __shfl_xor(s[k], 8);
            s[k] += __shfl_xor(s[k], 16);
            s[k] += __shfl_xor(s[k], 32);
        }
        if (eo == 0) {
            const int d = e1 - e0;
            const float inv = 1.f / (float)(d < 1 ? 1 : d);
            unsigned short pk[8];
#pragma unroll
            for (int k = 0; k < 8; ++k) {
                float v = s[k] * inv + bias8[k];
                pk[k] = f2bf(v > 0.f ? v : 0.f);
            }
            const int lt = (nl & 7) * 2 + (c8 >> 2);
            const int o = lt * 256 + ((nl >> 3) + 8 * (c8 & 3)) * 8;
            *(uint4*)&s_hi[o] = *(const uint4*)pk;
        }
    }
    __syncthreads();
    for (int idx = tid; idx < 512; idx += 256) {
        int lt = idx >> 5, sub = idx & 31;
        int ln = sub & 7, qq = sub >> 3;
        size_t g2 = (size_t)(nt >> 1) * 32 + (lt >> 1) * 4 + 2 + (lt & 1);
        size_t dst = g2 * 512 + (size_t)((nt & 1) * 8 + ln + 16 * qq) * 8;
        int src = lt * 256 + (ln + 8 * qq) * 8;
        *(uint4*)&h1b[dst] = *(const uint4*)&s_hi[src];
    }
}

// == fused MLP (pure bf16 MFMA, 32 rows/block, 2-way A reg-block) ========
#define S1 264                                     // bf16 LDS row stride
__global__ __launch_bounds__(256) void k_mlp(const unsigned short* __restrict__ h1b,
                                             const unsigned short* __restrict__ w0tt,
                                             const float* __restrict__ b0,
                                             const unsigned short* __restrict__ w1tt,
                                             const float* __restrict__ b1,
                                             const float* __restrict__ w2,
                                             const float* __restrict__ b2,
                                             float* __restrict__ out) {
    __shared__ unsigned short xs[32 * S1];
    __shared__ unsigned short xs2[32 * S1];
    const int tid = threadIdx.x;
    const int wv = tid >> 6, l = tid & 63;
    const int lr = l & 15, lg = l >> 4;
    const int row0 = blockIdx.x * 32;

    f32x4 acc[2][4];
#pragma unroll
    for (int t = 0; t < 4; ++t) {
        float bv = b0[wv * 64 + t * 16 + lr];
        acc[0][t] = (f32x4){bv, bv, bv, bv};
        acc[1][t] = (f32x4){bv, bv, bv, bv};
    }
    const size_t at0 = (size_t)(blockIdx.x * 2) * 32;
    for (int kc = 0; kc < 32; ++kc) {
        bf16x8 a0 = *(const bf16x8*)(h1b + (at0 + kc) * 512 + l * 8);
        bf16x8 a1 = *(const bf16x8*)(h1b + (at0 + 32 + kc) * 512 + l * 8);
#pragma unroll
        for (int t = 0; t < 4; ++t) {
            bf16x8 b = *(const bf16x8*)(w0tt + ((size_t)(wv * 4 + t) * 32 + kc) * 512 + l * 8);
            acc[0][t] = __builtin_amdgcn_mfma_f32_16x16x32_bf16(a0, b, acc[0][t], 0, 0, 0);
            acc[1][t] = __builtin_amdgcn_mfma_f32_16x16x32_bf16(a1, b, acc[1][t], 0, 0, 0);
        }
    }
#pragma unroll
    for (int h = 0; h < 2; ++h)
#pragma unroll
        for (int t = 0; t < 4; ++t)
#pragma unroll
            for (int r = 0; r < 4; ++r)
                xs[(h * 16 + lg * 4 + r) * S1 + wv * 64 + t * 16 + lr] = f2bf(tanhf(acc[h][t][r]));
    __syncthreads();

    f32x4 acc2[2][4];
#pragma unroll
    for (int t = 0; t < 4; ++t) {
        float bv = b1[wv * 64 + t * 16 + lr];
        acc2[0][t] = (f32x4){bv, bv, bv, bv};
        acc2[1][t] = (f32x4){bv, bv, bv, bv};
    }
    for (int kc = 0; kc < 8; ++kc) {
        bf16x8 a0 = *(const bf16x8*)(xs + lr * S1 + kc * 32 + lg * 8);
        bf16x8 a1 = *(const bf16x8*)(xs + (16 + lr) * S1 + kc * 32 + lg * 8);
#pragma unroll
        for (int t = 0; t < 4; ++t) {
            bf16x8 b = *(const bf16x8*)(w1tt + ((size_t)(wv * 4 + t) * 8 + kc) * 512 + l * 8);
            acc2[0][t] = __builtin_amdgcn_mfma_f32_16x16x32_bf16(a0, b, acc2[0][t], 0, 0, 0);
            acc2[1][t] = __builtin_amdgcn_mfma_f32_16x16x32_bf16(a1, b, acc2[1][t], 0, 0, 0);
        }
    }
#pragma unroll
    for (int h = 0; h < 2; ++h)
#pragma unroll
        for (int t = 0; t < 4; ++t)
#pragma unroll
            for (int r = 0; r < 4; ++r)
                xs2[(h * 16 + lg * 4 + r) * S1 + wv * 64 + t * 16 + lr] = f2bf(tanhf(acc2[h][t][r]));
    __syncthreads();

    {
        const int row = tid >> 3, seg = tid & 7;
        float p = 0.f;
#pragma unroll
        for (int c = 0; c < 32; ++c)
            p += bf2f(xs2[row * S1 + seg * 32 + c]) * w2[seg * 32 + c];
        p += __shfl_xor(p, 1);
        p += __shfl_xor(p, 2);
        p += __shfl_xor(p, 4);
        if (seg == 0) out[row0 + row] = p + b2[0];
    }
}

extern "C" void kernel_launch(void* const* d_in, const int* in_sizes, int n_in,
                              void* d_out, int out_size, void* d_ws, size_t ws_size,
                              hipStream_t stream) {
    const float* obs  = (const float*)d_in[0];
    const int*   edge = (const int*)d_in[1];
    const float* ws0  = (const float*)d_in[2];
    const float* bs0  = (const float*)d_in[3];
    const float* wn0  = (const float*)d_in[4];
    const float* bn0  = (const float*)d_in[5];
    const float* ws1  = (const float*)d_in[6];
    const float* bs1  = (const float*)d_in[7];
    const float* wn1  = (const float*)d_in[8];
    const float* bn1  = (const float*)d_in[9];
    const float* w0   = (const float*)d_in[10];
    const float* b0   = (const float*)d_in[11];
    const float* w1   = (const float*)d_in[12];
    const float* b1   = (const float*)d_in[13];
    const float* w2   = (const float*)d_in[14];
    const float* b2   = (const float*)d_in[15];
    float* out = (float*)d_out;

    char* wsb = (char*)d_ws;
    // pairs (8 MB) and agg0 (8 MB) alias: pairs dead before k_agg0 writes.
    int2*  pairs  = (int2*)wsb;                                 // NE int2
    float* agg0   = (float*)wsb;                                // NN*16 f32
    int*   bcnt   = (int*)(wsb + (size_t)NE * 8);               // 256
    int*   bbase  = bcnt + 256;                                 // 257
    int*   bcur   = bbase + 257;                                // 256
    int*   off    = bcur + 256 + 3;                             // NN+1 (8B aligned)
    int*   csr    = off + NN + 1;                               // NE
    unsigned short* y1b     = (unsigned short*)(csr + NE + 1);  // NN*64
    unsigned short* h1b     = y1b + (size_t)NN * 64;            // ROWS*1024
    unsigned short* w0tt_hi = h1b + (size_t)ROWS * 1024;        // 256x1024
    unsigned short* w0tt_lo = w0tt_hi + 256 * 1024;
    unsigned short* w1tt_hi = w0tt_lo + 256 * 1024;             // 256x256
    unsigned short* w1tt_lo = w1tt_hi + 256 * 256;
    unsigned short* ws1tt_hi = w1tt_lo + 256 * 256;             // 64x128
    unsigned short* ws1tt_lo = ws1tt_hi + 64 * 128;
    unsigned short* wn1tt_hi = ws1tt_lo + 64 * 128;
    unsigned short* wn1tt_lo = wn1tt_hi + 64 * 128;
    unsigned short* obsb     = wn1tt_lo + 64 * 128;             // NN*16 bf16

    hipMemsetAsync(bcnt, 0, 256 * sizeof(int), stream);

    k_prepall<<<dim3(3392), dim3(256), 0, stream>>>(w0, w0tt_hi, w0tt_lo,
                                                    w1, w1tt_hi, w1tt_lo,
                                                    ws1, ws1tt_hi, ws1tt_lo,
                                                    wn1, wn1tt_hi, wn1tt_lo,
                                                    obs, obsb, edge, bcnt);

    k_scan256<<<dim3(1),         dim3(256), 0, stream>>>(bcnt, bbase, bcur);
    k_bucket <<<dim3(NE / 4096), dim3(256), 0, stream>>>(edge, bcur, pairs);
    k_degscan<<<dim3(256),       dim3(256), 0, stream>>>(pairs, bbase, off);
    k_sort   <<<dim3(256),       dim3(256), 0, stream>>>(pairs, bbase, off, csr);

    k_agg0   <<<dim3(NN * 16 / 256), dim3(256), 0, stream>>>(obsb, off, csr, agg0);
    k_f01    <<<dim3(NN / 64),       dim3(256), 0, stream>>>(obs, agg0, off, ws0, bs0, wn0, bn0,
                                                             ws1tt_hi, ws1tt_lo, wn1tt_hi, wn1tt_lo,
                                                             bs1, h1b, y1b);
    k_agg1f  <<<dim3(NN / 64),       dim3(256), 0, stream>>>(y1b, off, csr, bn1, h1b);
    k_mlp    <<<dim3(ROWS / 32),     dim3(256), 0, stream>>>(h1b, w0tt_hi, b0, w1tt_hi, b1, w2, b2, out);
}

// Round 19
// 185.665 us; speedup vs baseline: 1.0382x; 1.0382x over previous
//
#include <hip/hip_runtime.h>

#define STEPS 64
#define NUM_CPU 4
#define AGENTS 64
#define PHASES 8
#define NN (STEPS*NUM_CPU*AGENTS*PHASES)   // 131072 nodes
#define NE (NN*8)                          // 1048576 edges
#define ROWS (NN/PHASES)                   // 16384 MLP rows

typedef __attribute__((ext_vector_type(8))) short bf16x8;
typedef __attribute__((ext_vector_type(4))) float f32x4;

__device__ inline unsigned short f2bf(float x) {
    unsigned int b = __float_as_uint(x);
    return (unsigned short)((b + 0x7FFF + ((b >> 16) & 1)) >> 16);
}
__device__ inline float bf2f(unsigned short h) {
    return __uint_as_float(((unsigned int)h) << 16);
}
__device__ inline void split8(const float* a, bf16x8& hi, bf16x8& lo) {
#pragma unroll
    for (int i = 0; i < 8; ++i) {
        float x = a[i];
        unsigned short h = f2bf(x);
        hi[i] = (short)h;
        lo[i] = (short)f2bf(x - bf2f(h));
    }
}

// fragment-tile offset: value (n, k) lives at
//   ((n>>4)*TK + (k>>5))*512 + ((n&15) + 16*((k>>3)&3))*8 + (k&7),  TK=K/32.

// ===== combined prep: weight tiles + obs->bf16 table + coarse hist ======
__device__ inline void prep1(const float* __restrict__ src,
                             unsigned short* __restrict__ dhi,
                             unsigned short* __restrict__ dlo,
                             int gid, int nshift, int nmask, int tk) {
    int k = gid >> nshift, n = gid & nmask;
    float x = src[gid];
    unsigned short h = f2bf(x);
    size_t o = ((size_t)(n >> 4) * tk + (k >> 5)) * 512
             + ((n & 15) + 16 * ((k >> 3) & 3)) * 8 + (k & 7);
    dhi[o] = h;
    dlo[o] = f2bf(x - bf2f(h));
}

__global__ __launch_bounds__(256) void k_prepall(const float* __restrict__ w0,
                                                 unsigned short* __restrict__ w0hi,
                                                 unsigned short* __restrict__ w0lo,
                                                 const float* __restrict__ w1,
                                                 unsigned short* __restrict__ w1hi,
                                                 unsigned short* __restrict__ w1lo,
                                                 const float* __restrict__ ws1,
                                                 unsigned short* __restrict__ ws1hi,
                                                 unsigned short* __restrict__ ws1lo,
                                                 const float* __restrict__ wn1,
                                                 unsigned short* __restrict__ wn1hi,
                                                 unsigned short* __restrict__ wn1lo,
                                                 const float* __restrict__ obs,
                                                 unsigned short* __restrict__ obsb,
                                                 const int* __restrict__ edge,
                                                 int* __restrict__ bcnt) {
    __shared__ int c[256];
    const int blk = blockIdx.x, tid = threadIdx.x;
    if (blk < 1024) {
        prep1(w0, w0hi, w0lo, blk * 256 + tid, 8, 255, 32);
    } else if (blk < 1280) {
        prep1(w1, w1hi, w1lo, (blk - 1024) * 256 + tid, 8, 255, 8);
    } else if (blk < 1312) {
        prep1(ws1, ws1hi, ws1lo, (blk - 1280) * 256 + tid, 6, 63, 4);
    } else if (blk < 1344) {
        prep1(wn1, wn1hi, wn1lo, (blk - 1312) * 256 + tid, 6, 63, 4);
    } else if (blk < 2368) {
        int gid = (blk - 1344) * 256 + tid;
        const float* src = obs + (size_t)gid * 8;
        unsigned short v[8];
#pragma unroll
        for (int i = 0; i < 8; ++i) v[i] = f2bf(src[i]);
        *(uint4*)&obsb[(size_t)gid * 8] = *(const uint4*)v;
    } else {
        c[tid] = 0;
        __syncthreads();
        const int base = (blk - 2368) * 1024;
        for (int i = tid; i < 1024; i += 256)
            atomicAdd(&c[edge[NE + base + i] >> 9], 1);
        __syncthreads();
        atomicAdd(&bcnt[tid], c[tid]);
    }
}

__global__ __launch_bounds__(256) void k_scan256(const int* __restrict__ bcnt,
                                                 int* __restrict__ bbase,
                                                 int* __restrict__ bcur) {
    __shared__ int s[256];
    const int t = threadIdx.x;
    int v = bcnt[t];
    s[t] = v;
    __syncthreads();
    for (int d = 1; d < 256; d <<= 1) {
        int x = (t >= d) ? s[t - d] : 0;
        __syncthreads();
        s[t] += x;
        __syncthreads();
    }
    int ex = s[t] - v;
    bbase[t] = ex;
    bcur[t] = ex;
    if (t == 255) bbase[256] = s[255];
}

__global__ __launch_bounds__(256) void k_bucket(const int* __restrict__ edge,
                                                int* __restrict__ bcur,
                                                int2* __restrict__ pairs) {
    __shared__ int rs[4096], rd[4096];
    __shared__ int ss[4096], sd[4096];
    __shared__ int cnt[256], lbase[256], lcur[256], gbase[256];
    const int tid = threadIdx.x;
    const int e0 = blockIdx.x * 4096;
    cnt[tid] = 0;
    for (int i = tid; i < 4096; i += 256) {
        rs[i] = edge[e0 + i];
        rd[i] = edge[NE + e0 + i];
    }
    __syncthreads();
    for (int i = tid; i < 4096; i += 256) atomicAdd(&cnt[rd[i] >> 9], 1);
    __syncthreads();
    {
        const int v = cnt[tid];
        lbase[tid] = v;
        __syncthreads();
        for (int d = 1; d < 256; d <<= 1) {
            int x = (tid >= d) ? lbase[tid - d] : 0;
            __syncthreads();
            lbase[tid] += x;
            __syncthreads();
        }
        const int ex = lbase[tid] - v;
        lbase[tid] = ex;
        lcur[tid] = ex;
        gbase[tid] = atomicAdd(&bcur[tid], v);
    }
    __syncthreads();
    for (int i = tid; i < 4096; i += 256) {
        int b = rd[i] >> 9;
        int p = atomicAdd(&lcur[b], 1);
        ss[p] = rs[i];
        sd[p] = rd[i];
    }
    __syncthreads();
    for (int j = tid; j < 4096; j += 256) {
        int b = sd[j] >> 9;
        pairs[gbase[b] + (j - lbase[b])] = (int2){ss[j], sd[j]};
    }
}

// ==== per-bucket degree histogram + scan -> off (merged, no deg array) ==
__global__ __launch_bounds__(256) void k_degscan(const int2* __restrict__ pairs,
                                                 const int* __restrict__ bbase,
                                                 int* __restrict__ off) {
    __shared__ int c[512];
    __shared__ int s[256];
    const int b = blockIdx.x, tid = threadIdx.x;
    c[tid] = 0; c[tid + 256] = 0;
    __syncthreads();
    const int n0 = bbase[b], n1 = bbase[b + 1];
    for (int j = n0 + tid; j < n1; j += 256) atomicAdd(&c[pairs[j].y & 511], 1);
    __syncthreads();
    const int vx = c[tid * 2], vy = c[tid * 2 + 1];
    const int pair = vx + vy;
    s[tid] = pair;
    __syncthreads();
    for (int d = 1; d < 256; d <<= 1) {
        int x = (tid >= d) ? s[tid - d] : 0;
        __syncthreads();
        s[tid] += x;
        __syncthreads();
    }
    int pre = bbase[b] + s[tid] - pair;
    int i0 = b * 512 + tid * 2;
    off[i0] = pre;
    off[i0 + 1] = pre + vx;
    if (b == 255 && tid == 255) off[NN] = pre + pair;
}

__global__ __launch_bounds__(256) void k_sort(const int2* __restrict__ pairs,
                                              const int* __restrict__ bbase,
                                              const int* __restrict__ off,
                                              int* __restrict__ csr) {
    __shared__ int lcur[512];
    __shared__ int sorted[6144];
    const int b = blockIdx.x, tid = threadIdx.x;
    const int off0 = off[b * 512];
    lcur[tid] = off[b * 512 + tid] - off0;
    lcur[tid + 256] = off[b * 512 + 256 + tid] - off0;
    __syncthreads();
    const int n0 = bbase[b], n1 = bbase[b + 1];
    for (int j = n0 + tid; j < n1; j += 256) {
        int2 p = pairs[j];
        int loc = atomicAdd(&lcur[p.y & 511], 1);
        sorted[loc] = p.x;
    }
    __syncthreads();
    const int cnt = n1 - n0;
    for (int j = tid; j < cnt; j += 256) csr[off0 + j] = sorted[j];
}

// ====== layer 0: per-node aggregate of obs (bf16 table, 8-deep ILP) =====
__global__ __launch_bounds__(256) void k_agg0(const unsigned short* __restrict__ obsb,
                                              const int* __restrict__ off,
                                              const int* __restrict__ csr,
                                              float* __restrict__ agg0) {
    int gid = blockIdx.x * 256 + threadIdx.x;
    int node = gid >> 4, f = gid & 15;
    if (node >= NN) return;
    int e0 = off[node], e1 = off[node + 1];
    float s0 = 0.f, s1 = 0.f, s2 = 0.f, s3 = 0.f;
    float s4 = 0.f, s5 = 0.f, s6 = 0.f, s7 = 0.f;
    int e = e0;
    for (; e + 7 < e1; e += 8) {
        s0 += bf2f(obsb[csr[e] * 16 + f]);
        s1 += bf2f(obsb[csr[e + 1] * 16 + f]);
        s2 += bf2f(obsb[csr[e + 2] * 16 + f]);
        s3 += bf2f(obsb[csr[e + 3] * 16 + f]);
        s4 += bf2f(obsb[csr[e + 4] * 16 + f]);
        s5 += bf2f(obsb[csr[e + 5] * 16 + f]);
        s6 += bf2f(obsb[csr[e + 6] * 16 + f]);
        s7 += bf2f(obsb[csr[e + 7] * 16 + f]);
    }
    for (; e + 3 < e1; e += 4) {
        s0 += bf2f(obsb[csr[e] * 16 + f]);
        s1 += bf2f(obsb[csr[e + 1] * 16 + f]);
        s2 += bf2f(obsb[csr[e + 2] * 16 + f]);
        s3 += bf2f(obsb[csr[e + 3] * 16 + f]);
    }
    for (; e < e1; ++e) s0 += bf2f(obsb[csr[e] * 16 + f]);
    agg0[node * 16 + f] = ((s0 + s1) + (s2 + s3)) + ((s4 + s5) + (s6 + s7));
}

// ==== FUSED layer-0 transform + layer-1 GEMMs (MFMA hi/lo), 64 nodes/blk
__global__ __launch_bounds__(256) void k_f01(const float* __restrict__ obs,
                                             const float* __restrict__ agg0,
                                             const int* __restrict__ off,
                                             const float* __restrict__ ws0,
                                             const float* __restrict__ bs0,
                                             const float* __restrict__ wn0,
                                             const float* __restrict__ bn0,
                                             const unsigned short* __restrict__ ws1tt_hi,
                                             const unsigned short* __restrict__ ws1tt_lo,
                                             const unsigned short* __restrict__ wn1tt_hi,
                                             const unsigned short* __restrict__ wn1tt_lo,
                                             const float* __restrict__ bs1,
                                             unsigned short* __restrict__ h1b,
                                             unsigned short* __restrict__ y1b) {
    __shared__ float w0s[16 * 64];
    __shared__ float w0n[16 * 64];
    __shared__ float biasS[64], biasN[64];
    __shared__ __align__(16) unsigned short s_hi[16 * 256];
    const int tid = threadIdx.x;
    for (int t = tid; t < 1024; t += 256) { w0s[t] = ws0[t]; w0n[t] = wn0[t]; }
    if (tid < 64) { biasS[tid] = bs0[tid]; biasN[tid] = bn0[tid]; }
    __syncthreads();

    const int wv = tid >> 6, l = tid & 63;
    const int lr = l & 15, lg = l >> 4;
    const int nt = blockIdx.x;
    const int tile = nt * 4 + wv;
    const int node = tile * 16 + lr;

    float xin[16], ain[16];
    {
        const float* xp = obs + (size_t)node * 16;
        const float* ap = agg0 + (size_t)node * 16;
#pragma unroll
        for (int q = 0; q < 4; ++q) {
            *(float4*)&xin[q * 4] = *(const float4*)(xp + q * 4);
            *(float4*)&ain[q * 4] = *(const float4*)(ap + q * 4);
        }
        int d = off[node + 1] - off[node];
        float inv = 1.f / (float)(d < 1 ? 1 : d);
#pragma unroll
        for (int k = 0; k < 16; ++k) ain[k] *= inv;
    }

    bf16x8 ahi[4], alo[4];
#pragma unroll
    for (int kc = 0; kc < 4; ++kc) {
        const int half = kc >> 1;
        const int jb = (kc & 1) * 32 + lg * 8;
        const float* w = half ? w0n : w0s;
        const float* bias = half ? biasN : biasS;
        const float* in = half ? ain : xin;
        float a8[8];
#pragma unroll
        for (int i = 0; i < 8; ++i) a8[i] = bias[jb + i];
        for (int k = 0; k < 16; ++k) {
            const float xv = in[k];
            const float4 wa = *(const float4*)&w[k * 64 + jb];
            const float4 wb = *(const float4*)&w[k * 64 + jb + 4];
            a8[0] += xv * wa.x; a8[1] += xv * wa.y;
            a8[2] += xv * wa.z; a8[3] += xv * wa.w;
            a8[4] += xv * wb.x; a8[5] += xv * wb.y;
            a8[6] += xv * wb.z; a8[7] += xv * wb.w;
        }
#pragma unroll
        for (int i = 0; i < 8; ++i) a8[i] = a8[i] > 0.f ? a8[i] : 0.f;
        split8(a8, ahi[kc], alo[kc]);
    }

    f32x4 acc[8];
#pragma unroll
    for (int t = 0; t < 8; ++t) {
        float bv = (t < 4) ? bs1[t * 16 + lr] : 0.f;
        acc[t] = (f32x4){bv, bv, bv, bv};
    }
#pragma unroll
    for (int kc = 0; kc < 4; ++kc) {
#pragma unroll
        for (int t = 0; t < 8; ++t) {
            const unsigned short* bh = (t < 4) ? ws1tt_hi : wn1tt_hi;
            const unsigned short* bl = (t < 4) ? ws1tt_lo : wn1tt_lo;
            size_t boff = ((size_t)(t & 3) * 4 + kc) * 512 + l * 8;
            bf16x8 bhi = *(const bf16x8*)(bh + boff);
            bf16x8 blo = *(const bf16x8*)(bl + boff);
            acc[t] = __builtin_amdgcn_mfma_f32_16x16x32_bf16(ahi[kc], bhi, acc[t], 0, 0, 0);
            acc[t] = __builtin_amdgcn_mfma_f32_16x16x32_bf16(alo[kc], bhi, acc[t], 0, 0, 0);
            acc[t] = __builtin_amdgcn_mfma_f32_16x16x32_bf16(ahi[kc], blo, acc[t], 0, 0, 0);
        }
    }

#pragma unroll
    for (int t = 0; t < 8; ++t) {
#pragma unroll
        for (int r = 0; r < 4; ++r) {
            const int nl = wv * 16 + lg * 4 + r;
            const size_t gnode = (size_t)nt * 64 + nl;
            if (t < 4) {
                float v = acc[t][r];
                v = v > 0.f ? v : 0.f;
                const int c = t * 16 + lr;
                const int lt = (nl & 7) * 2 + (c >> 5);
                const int o = lt * 256 + ((nl >> 3) + 8 * ((c >> 3) & 3)) * 8 + (c & 7);
                s_hi[o] = f2bf(v);
            } else {
                y1b[gnode * 64 + (t - 4) * 16 + lr] = f2bf(acc[t][r]);
            }
        }
    }
    __syncthreads();
    for (int idx = tid; idx < 512; idx += 256) {
        int lt = idx >> 5, sub = idx & 31;
        int ln = sub & 7, qq = sub >> 3;
        size_t g = (size_t)(nt >> 1) * 32 + (lt >> 1) * 4 + (lt & 1);
        size_t dst = g * 512 + (size_t)((nt & 1) * 8 + ln + 16 * qq) * 8;
        int src = lt * 256 + (ln + 8 * qq) * 8;
        *(uint4*)&h1b[dst] = *(const uint4*)&s_hi[src];
    }
}

// ==== layer-1 neighbor aggregate (uint2 gather: 16 lanes/row x 4 edges) =
__global__ __launch_bounds__(256) void k_agg1f(const unsigned short* __restrict__ y1b,
                                               const int* __restrict__ off,
                                               const int* __restrict__ csr,
                                               const float* __restrict__ bn1,
                                               unsigned short* __restrict__ h1b) {
    __shared__ __align__(16) unsigned short s_hi[16 * 256];
    const int tid = threadIdx.x;
    const int wv = tid >> 6, lane = tid & 63;
    const int c4 = lane & 15, eo = lane >> 4;      // col-group, edge-offset
    const int nt = blockIdx.x;
    const int cbase = c4 * 4;
    const float4 bias4 = *(const float4*)&bn1[cbase];
    const int q = (cbase >> 3) & 3, e7b = cbase & 7, hi = cbase >> 5;

    for (int i = 0; i < 16; ++i) {
        const int nl = wv * 16 + i;
        const int node = nt * 64 + nl;
        const int e0 = off[node], e1 = off[node + 1];
        float a0 = 0.f, a1 = 0.f, a2 = 0.f, a3 = 0.f;
        float b0 = 0.f, b1 = 0.f, b2 = 0.f, b3 = 0.f;
        int e = e0;
        for (; e + 7 < e1; e += 8) {
            uint2 v0 = *(const uint2*)&y1b[(size_t)csr[e + eo] * 64 + cbase];
            uint2 v1 = *(const uint2*)&y1b[(size_t)csr[e + 4 + eo] * 64 + cbase];
            a0 += bf2f((unsigned short)v0.x); a1 += bf2f((unsigned short)(v0.x >> 16));
            a2 += bf2f((unsigned short)v0.y); a3 += bf2f((unsigned short)(v0.y >> 16));
            b0 += bf2f((unsigned short)v1.x); b1 += bf2f((unsigned short)(v1.x >> 16));
            b2 += bf2f((unsigned short)v1.y); b3 += bf2f((unsigned short)(v1.y >> 16));
        }
        int r = e1 - e;
        if (r >= 4) {
            uint2 v0 = *(const uint2*)&y1b[(size_t)csr[e + eo] * 64 + cbase];
            a0 += bf2f((unsigned short)v0.x); a1 += bf2f((unsigned short)(v0.x >> 16));
            a2 += bf2f((unsigned short)v0.y); a3 += bf2f((unsigned short)(v0.y >> 16));
            e += 4; r -= 4;
        }
        if (eo < r) {
            uint2 v0 = *(const uint2*)&y1b[(size_t)csr[e + eo] * 64 + cbase];
            b0 += bf2f((unsigned short)v0.x); b1 += bf2f((unsigned short)(v0.x >> 16));
            b2 += bf2f((unsigned short)v0.y); b3 += bf2f((unsigned short)(v0.y >> 16));
        }
        float s0 = a0 + b0, s1 = a1 + b1, s2 = a2 + b2, s3 = a3 + b3;
        s0 += __shfl_xor(s0, 16); s0 += __shfl_xor(s0, 32);
        s1 += __shfl_xor(s1, 16); s1 += __shfl_xor(s1, 32);
        s2 += __shfl_xor(s2, 16); s2 += __shfl_xor(s2, 32);
        s3 += __shfl_xor(s3, 16); s3 += __shfl_xor(s3, 32);
        if (eo == 0) {
            const int d = e1 - e0;
            const float inv = 1.f / (float)(d < 1 ? 1 : d);
            float v0 = s0 * inv + bias4.x; v0 = v0 > 0.f ? v0 : 0.f;
            float v1 = s1 * inv + bias4.y; v1 = v1 > 0.f ? v1 : 0.f;
            float v2 = s2 * inv + bias4.z; v2 = v2 > 0.f ? v2 : 0.f;
            float v3 = s3 * inv + bias4.w; v3 = v3 > 0.f ? v3 : 0.f;
            const int lt = (nl & 7) * 2 + hi;
            const int o = lt * 256 + ((nl >> 3) + 8 * q) * 8 + e7b;
            uint2 pack;
            pack.x = (unsigned)f2bf(v0) | ((unsigned)f2bf(v1) << 16);
            pack.y = (unsigned)f2bf(v2) | ((unsigned)f2bf(v3) << 16);
            *(uint2*)&s_hi[o] = pack;
        }
    }
    __syncthreads();
    for (int idx = tid; idx < 512; idx += 256) {
        int lt = idx >> 5, sub = idx & 31;
        int ln = sub & 7, qq = sub >> 3;
        size_t g2 = (size_t)(nt >> 1) * 32 + (lt >> 1) * 4 + 2 + (lt & 1);
        size_t dst = g2 * 512 + (size_t)((nt & 1) * 8 + ln + 16 * qq) * 8;
        int src = lt * 256 + (ln + 8 * qq) * 8;
        *(uint4*)&h1b[dst] = *(const uint4*)&s_hi[src];
    }
}

// == fused MLP (pure bf16 MFMA, 32 rows/block, 2-way A reg-block) ========
#define S1 264                                     // bf16 LDS row stride
__global__ __launch_bounds__(256) void k_mlp(const unsigned short* __restrict__ h1b,
                                             const unsigned short* __restrict__ w0tt,
                                             const float* __restrict__ b0,
                                             const unsigned short* __restrict__ w1tt,
                                             const float* __restrict__ b1,
                                             const float* __restrict__ w2,
                                             const float* __restrict__ b2,
                                             float* __restrict__ out) {
    __shared__ unsigned short xs[32 * S1];
    __shared__ unsigned short xs2[32 * S1];
    const int tid = threadIdx.x;
    const int wv = tid >> 6, l = tid & 63;
    const int lr = l & 15, lg = l >> 4;
    const int row0 = blockIdx.x * 32;

    f32x4 acc[2][4];
#pragma unroll
    for (int t = 0; t < 4; ++t) {
        float bv = b0[wv * 64 + t * 16 + lr];
        acc[0][t] = (f32x4){bv, bv, bv, bv};
        acc[1][t] = (f32x4){bv, bv, bv, bv};
    }
    const size_t at0 = (size_t)(blockIdx.x * 2) * 32;
    for (int kc = 0; kc < 32; ++kc) {
        bf16x8 a0 = *(const bf16x8*)(h1b + (at0 + kc) * 512 + l * 8);
        bf16x8 a1 = *(const bf16x8*)(h1b + (at0 + 32 + kc) * 512 + l * 8);
#pragma unroll
        for (int t = 0; t < 4; ++t) {
            bf16x8 b = *(const bf16x8*)(w0tt + ((size_t)(wv * 4 + t) * 32 + kc) * 512 + l * 8);
            acc[0][t] = __builtin_amdgcn_mfma_f32_16x16x32_bf16(a0, b, acc[0][t], 0, 0, 0);
            acc[1][t] = __builtin_amdgcn_mfma_f32_16x16x32_bf16(a1, b, acc[1][t], 0, 0, 0);
        }
    }
#pragma unroll
    for (int h = 0; h < 2; ++h)
#pragma unroll
        for (int t = 0; t < 4; ++t)
#pragma unroll
            for (int r = 0; r < 4; ++r)
                xs[(h * 16 + lg * 4 + r) * S1 + wv * 64 + t * 16 + lr] = f2bf(tanhf(acc[h][t][r]));
    __syncthreads();

    f32x4 acc2[2][4];
#pragma unroll
    for (int t = 0; t < 4; ++t) {
        float bv = b1[wv * 64 + t * 16 + lr];
        acc2[0][t] = (f32x4){bv, bv, bv, bv};
        acc2[1][t] = (f32x4){bv, bv, bv, bv};
    }
    for (int kc = 0; kc < 8; ++kc) {
        bf16x8 a0 = *(const bf16x8*)(xs + lr * S1 + kc * 32 + lg * 8);
        bf16x8 a1 = *(const bf16x8*)(xs + (16 + lr) * S1 + kc * 32 + lg * 8);
#pragma unroll
        for (int t = 0; t < 4; ++t) {
            bf16x8 b = *(const bf16x8*)(w1tt + ((size_t)(wv * 4 + t) * 8 + kc) * 512 + l * 8);
            acc2[0][t] = __builtin_amdgcn_mfma_f32_16x16x32_bf16(a0, b, acc2[0][t], 0, 0, 0);
            acc2[1][t] = __builtin_amdgcn_mfma_f32_16x16x32_bf16(a1, b, acc2[1][t], 0, 0, 0);
        }
    }
#pragma unroll
    for (int h = 0; h < 2; ++h)
#pragma unroll
        for (int t = 0; t < 4; ++t)
#pragma unroll
            for (int r = 0; r < 4; ++r)
                xs2[(h * 16 + lg * 4 + r) * S1 + wv * 64 + t * 16 + lr] = f2bf(tanhf(acc2[h][t][r]));
    __syncthreads();

    {
        const int row = tid >> 3, seg = tid & 7;
        float p = 0.f;
#pragma unroll
        for (int c = 0; c < 32; ++c)
            p += bf2f(xs2[row * S1 + seg * 32 + c]) * w2[seg * 32 + c];
        p += __shfl_xor(p, 1);
        p += __shfl_xor(p, 2);
        p += __shfl_xor(p, 4);
        if (seg == 0) out[row0 + row] = p + b2[0];
    }
}

extern "C" void kernel_launch(void* const* d_in, const int* in_sizes, int n_in,
                              void* d_out, int out_size, void* d_ws, size_t ws_size,
                              hipStream_t stream) {
    const float* obs  = (const float*)d_in[0];
    const int*   edge = (const int*)d_in[1];
    const float* ws0  = (const float*)d_in[2];
    const float* bs0  = (const float*)d_in[3];
    const float* wn0  = (const float*)d_in[4];
    const float* bn0  = (const float*)d_in[5];
    const float* ws1  = (const float*)d_in[6];
    const float* bs1  = (const float*)d_in[7];
    const float* wn1  = (const float*)d_in[8];
    const float* bn1  = (const float*)d_in[9];
    const float* w0   = (const float*)d_in[10];
    const float* b0   = (const float*)d_in[11];
    const float* w1   = (const float*)d_in[12];
    const float* b1   = (const float*)d_in[13];
    const float* w2   = (const float*)d_in[14];
    const float* b2   = (const float*)d_in[15];
    float* out = (float*)d_out;

    char* wsb = (char*)d_ws;
    // pairs (8 MB) and agg0 (8 MB) alias: pairs dead before k_agg0 writes.
    int2*  pairs  = (int2*)wsb;                                 // NE int2
    float* agg0   = (float*)wsb;                                // NN*16 f32
    int*   bcnt   = (int*)(wsb + (size_t)NE * 8);               // 256
    int*   bbase  = bcnt + 256;                                 // 257
    int*   bcur   = bbase + 257;                                // 256
    int*   off    = bcur + 256 + 3;                             // NN+1 (8B aligned)
    int*   csr    = off + NN + 1;                               // NE
    unsigned short* y1b     = (unsigned short*)(csr + NE + 1);  // NN*64
    unsigned short* h1b     = y1b + (size_t)NN * 64;            // ROWS*1024
    unsigned short* w0tt_hi = h1b + (size_t)ROWS * 1024;        // 256x1024
    unsigned short* w0tt_lo = w0tt_hi + 256 * 1024;
    unsigned short* w1tt_hi = w0tt_lo + 256 * 1024;             // 256x256
    unsigned short* w1tt_lo = w1tt_hi + 256 * 256;
    unsigned short* ws1tt_hi = w1tt_lo + 256 * 256;             // 64x128
    unsigned short* ws1tt_lo = ws1tt_hi + 64 * 128;
    unsigned short* wn1tt_hi = ws1tt_lo + 64 * 128;
    unsigned short* wn1tt_lo = wn1tt_hi + 64 * 128;
    unsigned short* obsb     = wn1tt_lo + 64 * 128;             // NN*16 bf16

    hipMemsetAsync(bcnt, 0, 256 * sizeof(int), stream);

    k_prepall<<<dim3(3392), dim3(256), 0, stream>>>(w0, w0tt_hi, w0tt_lo,
                                                    w1, w1tt_hi, w1tt_lo,
                                                    ws1, ws1tt_hi, ws1tt_lo,
                                                    wn1, wn1tt_hi, wn1tt_lo,
                                                    obs, obsb, edge, bcnt);

    k_scan256<<<dim3(1),         dim3(256), 0, stream>>>(bcnt, bbase, bcur);
    k_bucket <<<dim3(NE / 4096), dim3(256), 0, stream>>>(edge, bcur, pairs);
    k_degscan<<<dim3(256),       dim3(256), 0, stream>>>(pairs, bbase, off);
    k_sort   <<<dim3(256),       dim3(256), 0, stream>>>(pairs, bbase, off, csr);

    k_agg0   <<<dim3(NN * 16 / 256), dim3(256), 0, stream>>>(obsb, off, csr, agg0);
    k_f01    <<<dim3(NN / 64),       dim3(256), 0, stream>>>(obs, agg0, off, ws0, bs0, wn0, bn0,
                                                             ws1tt_hi, ws1tt_lo, wn1tt_hi, wn1tt_lo,
                                                             bs1, h1b, y1b);
    k_agg1f  <<<dim3(NN / 64),       dim3(256), 0, stream>>>(y1b, off, csr, bn1, h1b);
    k_mlp    <<<dim3(ROWS / 32),     dim3(256), 0, stream>>>(h1b, w0tt_hi, b0, w1tt_hi, b1, w2, b2, out);
}